// Round 4
// baseline (211.755 us; speedup 1.0000x reference)
//
#include <hip/hip_runtime.h>

// SmoothTopKGate: per row of 8 floats, solve sum_i sigmoid((s_i - theta)/tau) = k
// (k=2, tau=0.01) by safeguarded Newton, then emit the sigmoids.
//
// R4: two lanes per row; lane pairs cooperate via __shfl_xor(.,1) (DPP, no LDS).
// R7: ITEMS=2 + linearized final emit + nontemporal — NEUTRAL (kernel pinned
//     at ~55-57us vs 41us memory floor; TRANS-cut and ILP didn't move it).
// R8 (this round): theory = bursty memory shape. 62.5k short-lived waves each
//     burst 2 loads, compute ~800cy silent, burst 2 stores, exit. Convert to
//     PERSISTENT GRID-STRIDE: 3125 blocks x 256 thr = 800k threads, exactly
//     10 iterations each (8M float4 / 800k), with next-iteration prefetch
//     issued before the current solve -> continuous per-wave load+store
//     stream, 10x launch amortization, zero tail divergence (stride even:
//     lane-pair shuffle partners stay aligned).
//
// NOTE (correctness trap, do not "optimize"): g must be accumulated from the
// individual products m*(1-m) (or an fmaf chain thereof), NOT as
// f+2-sum(m^2) — catastrophic cancellation for ~40*tau gaps slams theta to
// the clamp bound (absmax ~0.95).

typedef float f32x4 __attribute__((ext_vector_type(4)));

__global__ __launch_bounds__(256) void smooth_topk_kernel(
    const float* __restrict__ s, float* __restrict__ out, int n) {
  const int stride = gridDim.x * blockDim.x;
  int idx = blockIdx.x * blockDim.x + threadIdx.x;

  const float C = 144.26950408889634f;      // 1/(tau*ln2), tau = 0.01
  const float LOG2E = 1.4426950408889634f;
  const float LN2 = 0.6931471805599453f;

  f32x4 vnext = {0.0f, 0.0f, 0.0f, 0.0f};
  if (idx < n)
    vnext = __builtin_nontemporal_load(reinterpret_cast<const f32x4*>(s) + idx);

  while (idx < n) {
    // ---- consume prefetched tile; immediately issue next iteration's load ----
    f32x4 v4 = vnext;
    int idx2 = idx + stride;
    if (idx2 < n)  // uniform-true except the last trip (grid divides n exactly)
      vnext = __builtin_nontemporal_load(reinterpret_cast<const f32x4*>(s) + idx2);

    float v0 = v4.x * C, v1 = v4.y * C, v2 = v4.z * C, v3 = v4.w * C;

    // ---- top-3 of my quad (p1 >= p2 >= p3), scaled domain ----
    float a = fmaxf(v0, v1), b = fminf(v0, v1);
    float c = fmaxf(v2, v3), d = fminf(v2, v3);
    float mn = fminf(a, c);
    float p1 = fmaxf(a, c);
    float p2 = fmaxf(mn, fmaxf(b, d));
    float p3 = __builtin_amdgcn_fmed3f(b, d, mn);

    // ---- partner quad's top-3 via xor-1 shuffle (DPP quad_perm) ----
    float q1 = __shfl_xor(p1, 1, 64);
    float q2 = __shfl_xor(p2, 1, 64);
    float q3 = __shfl_xor(p3, 1, 64);

    // 2nd and 3rd largest of the union (symmetric in p<->q: both lanes agree)
    float t2 = fmaxf(fminf(p1, q1), fmaxf(p2, q2));
    float t3 = fmaxf(fmaxf(fminf(p2, q1), fminf(p1, q2)), fmaxf(p3, q3));

    float phi = 0.5f * (t2 + t3);  // scaled theta; exact for 2-active case
    const float lo = t3 - 4.33f;   // root provably within ~0.025/tau scaled
    const float hi = t2 + 4.33f;

    // ---- 2 full Newton iterations ----
#pragma unroll
    for (int it = 0; it < 2; ++it) {
      float e0 = __builtin_amdgcn_exp2f(phi - v0);
      float e1 = __builtin_amdgcn_exp2f(phi - v1);
      float e2 = __builtin_amdgcn_exp2f(phi - v2);
      float e3 = __builtin_amdgcn_exp2f(phi - v3);
      float m0 = __builtin_amdgcn_rcpf(1.0f + e0);  // rcp(inf)=0: no NaN
      float m1 = __builtin_amdgcn_rcpf(1.0f + e1);
      float m2 = __builtin_amdgcn_rcpf(1.0f + e2);
      float m3 = __builtin_amdgcn_rcpf(1.0f + e3);
      float fh = (m0 + m1) + (m2 + m3);
      float gh = fmaf(m0, 1.0f - m0, fmaf(m1, 1.0f - m1,
                 fmaf(m2, 1.0f - m2, m3 * (1.0f - m3))));
      float f = (fh + __shfl_xor(fh, 1, 64)) - 2.0f;  // commutative: lanes agree
      float g = gh + __shfl_xor(gh, 1, 64);
      float step = f * LOG2E * __builtin_amdgcn_rcpf(fmaxf(g, 1e-12f));
      phi = fminf(fmaxf(phi + step, lo), hi);
    }

    // ---- final iteration: compute m, take step, emit linearized sigmoids ----
    {
      float e0 = __builtin_amdgcn_exp2f(phi - v0);
      float e1 = __builtin_amdgcn_exp2f(phi - v1);
      float e2 = __builtin_amdgcn_exp2f(phi - v2);
      float e3 = __builtin_amdgcn_exp2f(phi - v3);
      float m0 = __builtin_amdgcn_rcpf(1.0f + e0);
      float m1 = __builtin_amdgcn_rcpf(1.0f + e1);
      float m2 = __builtin_amdgcn_rcpf(1.0f + e2);
      float m3 = __builtin_amdgcn_rcpf(1.0f + e3);
      float c0 = m0 * (1.0f - m0);
      float c1 = m1 * (1.0f - m1);
      float c2 = m2 * (1.0f - m2);
      float c3 = m3 * (1.0f - m3);
      float fh = (m0 + m1) + (m2 + m3);
      float gh = (c0 + c1) + (c2 + c3);
      float f = (fh + __shfl_xor(fh, 1, 64)) - 2.0f;
      float g = gh + __shfl_xor(gh, 1, 64);
      float step = f * LOG2E * __builtin_amdgcn_rcpf(fmaxf(g, 1e-12f));
      float phin = fminf(fmaxf(phi + step, lo), hi);
      float w = (phin - phi) * LN2;  // actual (clamped) delta, in ln-units

      f32x4 o;
      o.x = fmaf(-w, c0, m0);
      o.y = fmaf(-w, c1, m1);
      o.z = fmaf(-w, c2, m2);
      o.w = fmaf(-w, c3, m3);
      __builtin_nontemporal_store(o, reinterpret_cast<f32x4*>(out) + idx);
    }

    idx = idx2;
  }
}

extern "C" void kernel_launch(void* const* d_in, const int* in_sizes, int n_in,
                              void* d_out, int out_size, void* d_ws, size_t ws_size,
                              hipStream_t stream) {
  const float* s = (const float*)d_in[0];
  float* out = (float*)d_out;
  int nhalf = in_sizes[0] / 4;  // number of float4 half-rows (2 per row)
  int block = 256;
  // Persistent grid-stride: ~10 items per thread. For nhalf = 8,000,000 this
  // gives grid = 3125, which divides the work exactly (no tail divergence).
  int grid = (nhalf + block * 10 - 1) / (block * 10);
  int max_grid = (nhalf + block - 1) / block;
  if (grid > max_grid) grid = max_grid;
  if (grid < 1) grid = 1;
  smooth_topk_kernel<<<grid, block, 0, stream>>>(s, out, nhalf);
}